// Round 3
// baseline (2124.266 us; speedup 1.0000x reference)
//
#include <hip/hip_runtime.h>
#include <stdint.h>

#define NK 27
#define HC 32
#define WPADF 33   // padded LDS row stride (f32): half-row reads offset by 16 banks -> 2 lanes/bank (free)

// stage 27x32x32 f32 weight into LDS with row padding (rows of 32 f32 -> stride 33)
__device__ __forceinline__ void stage_w27(const float* __restrict__ W, float* __restrict__ lds) {
    for (int i = threadIdx.x; i < NK * 32 * 32; i += blockDim.x) {
        int r = i >> 5, j = i & 31;
        lds[r * WPADF + j] = W[i];
    }
}

// one wave handles one point; lanes = (o in 0..31) x (c-half h in 0..1)
// returns un-activated conv sum (no bias) for output channel o=lane&31
__device__ __forceinline__ float sconv_point(
    const float* __restrict__ src, const int* __restrict__ nbr,
    long long N, long long n, const float* __restrict__ wl, int lane)
{
    const int o = lane & 31, h = lane >> 5;
    int idxv = -1;
    if (lane < NK) idxv = nbr[(long long)lane * N + n];
    unsigned long long mask = __ballot(idxv >= 0);
    float acc = 0.f;
    int k = -1; float rowv = 0.f;
    if (mask) {
        k = (int)__builtin_ctzll(mask); mask &= mask - 1;
        int idx = __shfl(idxv, k, 64);
        rowv = src[(long long)idx * HC + o];
    }
    while (k >= 0) {
        int kn = -1; float rown = 0.f;
        if (mask) {  // prefetch next valid neighbor row
            kn = (int)__builtin_ctzll(mask); mask &= mask - 1;
            int idx = __shfl(idxv, kn, 64);
            rown = src[(long long)idx * HC + o];
        }
        int base = (k * 32 + h * 16) * WPADF + o;
        #pragma unroll
        for (int cc = 0; cc < 16; ++cc) {
            float xv = __shfl(rowv, h * 16 + cc, 64);
            acc = fmaf(wl[base + cc * WPADF], xv, acc);
        }
        k = kn; rowv = rown;
    }
    acc += __shfl_xor(acc, 32, 64);  // combine the two c-halves
    return acc;
}

// K1: y = x @ Wg1 + bg1 ; split into cv (cols 0..31) and gl (cols 32..63)
__global__ __launch_bounds__(256) void k1_gemm(
    const float* __restrict__ x, const float* __restrict__ Wg1, const float* __restrict__ bg1,
    float* __restrict__ cv, float* __restrict__ gl, long long N)
{
    const int lane = threadIdx.x & 63;
    const long long wave = (long long)blockIdx.x * 4 + (threadIdx.x >> 6);
    const int C1 = 64;
    long long n0 = wave * C1;
    if (n0 >= N) return;
    float wcol[64];
    #pragma unroll
    for (int c = 0; c < 64; ++c) wcol[c] = Wg1[c * 64 + lane];
    const float bias = bg1[lane];
    long long n1 = n0 + C1; if (n1 > N) n1 = N;
    for (long long n = n0; n < n1; ++n) {
        float xr = x[n * 64 + lane];
        float acc = bias;
        #pragma unroll
        for (int c = 0; c < 64; ++c) acc = fmaf(__shfl(xr, c, 64), wcol[c], acc);
        if (lane < HC) cv[n * HC + lane] = acc;
        else           gl[n * HC + (lane - HC)] = acc;
    }
}

// K2a: r1 = relu(sconv(cv, Wr1) + br1)
__global__ __launch_bounds__(256) void k2a_conv(
    const float* __restrict__ cv, const int* __restrict__ nbr,
    const float* __restrict__ Wr1, const float* __restrict__ br1,
    float* __restrict__ r1, long long N)
{
    __shared__ float wlds[NK * 32 * WPADF];
    stage_w27(Wr1, wlds);
    __syncthreads();
    const int lane = threadIdx.x & 63;
    const long long wave = (long long)blockIdx.x * 4 + (threadIdx.x >> 6);
    const int C = 16;
    long long n0 = wave * C, n1 = n0 + C; if (n1 > N) n1 = N;
    const float bias = br1[lane & 31];
    for (long long n = n0; n < n1; ++n) {
        float v = fmaxf(sconv_point(cv, nbr, N, n, wlds, lane) + bias, 0.f);
        if (lane < HC) r1[n * HC + lane] = v;
    }
}

// K2b1: out1 = relu(sconv(gl, Wq1) + bq1) -> s12 ; m1 = rowmean(out1)
__global__ __launch_bounds__(256) void k2b1_conv(
    const float* __restrict__ gl, const int* __restrict__ nbr,
    const float* __restrict__ Wq1, const float* __restrict__ bq1,
    float* __restrict__ s12, float* __restrict__ m1, long long N)
{
    __shared__ float wlds[NK * 32 * WPADF];
    stage_w27(Wq1, wlds);
    __syncthreads();
    const int lane = threadIdx.x & 63;
    const long long wave = (long long)blockIdx.x * 4 + (threadIdx.x >> 6);
    const int C = 16;
    long long n0 = wave * C, n1 = n0 + C; if (n1 > N) n1 = N;
    const float bias = bq1[lane & 31];
    for (long long n = n0; n < n1; ++n) {
        float v = fmaxf(sconv_point(gl, nbr, N, n, wlds, lane) + bias, 0.f);
        float sm = v;
        #pragma unroll
        for (int d = 1; d < 32; d <<= 1) sm += __shfl_xor(sm, d, 64);
        if (lane < HC) s12[n * HC + lane] = v;
        if (lane == 0) m1[n] = sm * (1.f / 32.f);
    }
}

// K2b2: out2 = relu(sconv(gl, Wq2) + bq2) ; s12 += out2 ; batch sums of out2
__global__ __launch_bounds__(256) void k2b2_conv(
    const float* __restrict__ gl, const int* __restrict__ nbr,
    const float* __restrict__ Wq2, const float* __restrict__ bq2,
    const int* __restrict__ batch_id,
    float* __restrict__ s12, float* __restrict__ bsum, long long N)
{
    __shared__ float wlds[NK * 32 * WPADF];
    __shared__ float lbs[256];
    stage_w27(Wq2, wlds);
    lbs[threadIdx.x] = 0.f;
    __syncthreads();
    const int lane = threadIdx.x & 63;
    const long long wave = (long long)blockIdx.x * 4 + (threadIdx.x >> 6);
    const int C = 16;
    long long n0 = wave * C, n1 = n0 + C; if (n1 > N) n1 = N;
    const float bias = bq2[lane & 31];
    for (long long n = n0; n < n1; ++n) {
        float v = fmaxf(sconv_point(gl, nbr, N, n, wlds, lane) + bias, 0.f);
        int b = batch_id[n];
        if (lane < HC) {
            s12[n * HC + lane] += v;
            atomicAdd(&lbs[b * HC + lane], v);
        }
    }
    __syncthreads();
    atomicAdd(&bsum[threadIdx.x], lbs[threadIdx.x]);
}

// K3: r2 conv + full fused epilogue, f32 output
__global__ __launch_bounds__(256) void k3_final(
    const float* __restrict__ r1, const float* __restrict__ cv, const float* __restrict__ gl,
    const float* __restrict__ s12, const float* __restrict__ m1, const float* __restrict__ bsum,
    const int* __restrict__ nbr, const int* __restrict__ batch_id,
    const float* __restrict__ Wr2, const float* __restrict__ br2,
    const float* __restrict__ Wq3, const float* __restrict__ bq3,
    const float* __restrict__ Wg2, const float* __restrict__ bg2,
    const float* __restrict__ x, float* __restrict__ out,
    long long N, const int* __restrict__ bsz)
{
    __shared__ float wlds[NK * 32 * WPADF];
    stage_w27(Wr2, wlds);
    __syncthreads();
    const int lane = threadIdx.x & 63;
    const int o = lane & 31;
    float wq3c[32], wg2c[64];
    #pragma unroll
    for (int c = 0; c < 32; ++c) wq3c[c] = Wq3[c * 32 + o];
    #pragma unroll
    for (int c = 0; c < 64; ++c) wg2c[c] = Wg2[c * 64 + lane];
    const float bq3v = bq3[o];
    const float bg2v = bg2[lane];
    const float br2v = br2[o];
    const int B = *bsz;
    const float invNP = (float)B / (float)N;

    const long long wave = (long long)blockIdx.x * 4 + (threadIdx.x >> 6);
    const int C = 16;
    long long n0 = wave * C, n1 = n0 + C; if (n1 > N) n1 = N;
    for (long long n = n0; n < n1; ++n) {
        float r2 = fmaxf(sconv_point(r1, nbr, N, n, wlds, lane) + br2v, 0.f);
        float cx2 = r2 + 2.f * cv[n * HC + o];
        int b = batch_id[n];
        float m2v = bsum[b * HC + o] * invNP;
        float enc = sqrtf(m1[n] * m2v + 1e-12f);
        float fin = enc + s12[n * HC + o];
        float facc = bq3v;
        #pragma unroll
        for (int c = 0; c < 32; ++c) facc = fmaf(__shfl(fin, c, 64), wq3c[c], facc);
        float f = fmaxf(facc, 0.f);
        float glo = fmaxf(gl[n * HC + o] - f, 0.f);
        float racc = bg2v;
        #pragma unroll
        for (int c = 0; c < 32; ++c) racc = fmaf(__shfl(cx2, c, 64), wg2c[c], racc);
        #pragma unroll
        for (int c = 0; c < 32; ++c) racc = fmaf(__shfl(glo, c, 64), wg2c[32 + c], racc);
        out[n * 64 + lane] = x[n * 64 + lane] + racc;
    }
}

extern "C" void kernel_launch(void* const* d_in, const int* in_sizes, int n_in,
                              void* d_out, int out_size, void* d_ws, size_t ws_size,
                              hipStream_t stream) {
    const float* x   = (const float*)d_in[0];
    const float* Wg1 = (const float*)d_in[1];
    const float* bg1 = (const float*)d_in[2];
    const float* Wg2 = (const float*)d_in[3];
    const float* bg2 = (const float*)d_in[4];
    const float* Wr1 = (const float*)d_in[5];
    const float* br1 = (const float*)d_in[6];
    const float* Wr2 = (const float*)d_in[7];
    const float* br2 = (const float*)d_in[8];
    const float* Wq1 = (const float*)d_in[9];
    const float* bq1 = (const float*)d_in[10];
    const float* Wq2 = (const float*)d_in[11];
    const float* bq2 = (const float*)d_in[12];
    const float* Wq3 = (const float*)d_in[13];
    const float* bq3 = (const float*)d_in[14];
    const int* nbr   = (const int*)d_in[15];
    const int* bid   = (const int*)d_in[16];
    const int* bsz   = (const int*)d_in[17];

    const long long N = (long long)in_sizes[0] / 64;

    float* cv   = (float*)d_ws;
    float* gl   = cv  + N * 32;
    float* r1   = gl  + N * 32;
    float* s12  = r1  + N * 32;
    float* m1   = s12 + N * 32;
    float* bsum = m1  + N;          // 256 floats

    float* out = (float*)d_out;

    hipMemsetAsync(bsum, 0, 256 * sizeof(float), stream);

    // K1: 4 waves/block, 64 points/wave
    {
        long long waves = (N + 63) / 64;
        int blocks = (int)((waves + 3) / 4);
        k1_gemm<<<blocks, 256, 0, stream>>>(x, Wg1, bg1, cv, gl, N);
    }
    // conv kernels: 4 waves/block, 16 points/wave
    long long waves = (N + 15) / 16;
    int cblocks = (int)((waves + 3) / 4);
    k2a_conv<<<cblocks, 256, 0, stream>>>(cv, nbr, Wr1, br1, r1, N);
    k2b1_conv<<<cblocks, 256, 0, stream>>>(gl, nbr, Wq1, bq1, s12, m1, N);
    k2b2_conv<<<cblocks, 256, 0, stream>>>(gl, nbr, Wq2, bq2, bid, s12, bsum, N);
    k3_final<<<cblocks, 256, 0, stream>>>(r1, cv, gl, s12, m1, bsum, nbr, bid,
                                          Wr2, br2, Wq3, bq3, Wg2, bg2, x, out, N, bsz);
}

// Round 4
// 790.662 us; speedup vs baseline: 2.6867x; 2.6867x over previous
//
#include <hip/hip_runtime.h>
#include <stdint.h>

typedef unsigned int u32;
typedef unsigned short u16;
typedef unsigned long long u64;

#define HC 32
#define CPT 16   // points per wave in conv kernels

__device__ __forceinline__ float u2f(u32 u){ union{u32 i;float f;}v; v.i=u; return v.f; }
__device__ __forceinline__ u16 f2bf(float f){ union{float f;u32 i;}v; v.f=f; u32 i=v.i;
    return (u16)((i + 0x7FFFu + ((i>>16)&1u))>>16); }  // RNE

// ---- staging: 26 sparse k-slices (skip k=13), bf16x2 c-pairs: [k'][row=h*8+cc2][o] ----
__device__ __forceinline__ void stage_w26(const float* __restrict__ W, u32* __restrict__ wl, int nthr) {
    for (int i = threadIdx.x; i < 26*512; i += nthr) {
        int o = i & 31, row = (i >> 5) & 15, kp = i >> 9;
        int k = kp + (kp >= 13 ? 1 : 0);
        int c0 = (row >> 3)*16 + (row & 7)*2;
        float a = W[k*1024 + c0*32 + o];
        float b = W[k*1024 + (c0+1)*32 + o];
        wl[i] = (u32)f2bf(a) | ((u32)f2bf(b) << 16);
    }
}

__device__ __forceinline__ void load_self(const float* __restrict__ W, float* ws, int o, int h) {
    #pragma unroll
    for (int cc = 0; cc < 16; ++cc) ws[cc] = W[13*1024 + (h*16+cc)*32 + o];
}

// conv for one point: self (k=13) f32 reg weights; sparse k from LDS bf16x2 pairs
__device__ __forceinline__ float conv_pt(
    const float* __restrict__ src, float selfv, int idxv, u64 mask,
    const u32* __restrict__ wl, const float* __restrict__ ws, int o, int h)
{
    float acc = 0.f;
    int k = -1; float rowv = 0.f;
    if (mask) {  // start first sparse gather before self-MACs (hide latency)
        k = (int)__builtin_ctzll(mask); mask &= mask-1;
        int idx = __shfl(idxv, k, 64);
        rowv = src[(long long)idx*HC + o];
    }
    #pragma unroll
    for (int cc = 0; cc < 16; ++cc)
        acc = fmaf(ws[cc], __shfl(selfv, h*16+cc, 64), acc);
    while (k >= 0) {
        int kn = -1; float rown = 0.f;
        if (mask) {
            kn = (int)__builtin_ctzll(mask); mask &= mask-1;
            int idx = __shfl(idxv, kn, 64);
            rown = src[(long long)idx*HC + o];
        }
        int ks = k - (k > 13 ? 1 : 0);
        const u32* wp = wl + ks*512 + h*256 + o;
        #pragma unroll
        for (int cc2 = 0; cc2 < 8; ++cc2) {
            u32 wv = wp[cc2*32];
            float xv0 = __shfl(rowv, h*16 + 2*cc2, 64);
            float xv1 = __shfl(rowv, h*16 + 2*cc2 + 1, 64);
            acc = fmaf(u2f(wv << 16), xv0, acc);
            acc = fmaf(u2f(wv & 0xffff0000u), xv1, acc);
        }
        k = kn; rowv = rown;
    }
    acc += __shfl_xor(acc, 32, 64);
    return acc;
}

// K1: y = x @ Wg1 + bg1 -> cv | gl
__global__ __launch_bounds__(256, 3) void k1_gemm(
    const float* __restrict__ x, const float* __restrict__ Wg1, const float* __restrict__ bg1,
    float* __restrict__ cv, float* __restrict__ gl, long long N)
{
    const int lane = threadIdx.x & 63;
    const long long wave = (long long)blockIdx.x * 4 + (threadIdx.x >> 6);
    const int C1 = 32;
    long long n0 = wave * C1;
    if (n0 >= N) return;
    float wcol[64];
    #pragma unroll
    for (int c = 0; c < 64; ++c) wcol[c] = Wg1[c * 64 + lane];
    const float bias = bg1[lane];
    long long n1 = n0 + C1; if (n1 > N) n1 = N;
    for (long long n = n0; n < n1; ++n) {
        float xr = x[n * 64 + lane];
        float acc = bias;
        #pragma unroll
        for (int c = 0; c < 64; ++c) acc = fmaf(__shfl(xr, c, 64), wcol[c], acc);
        if (lane < HC) cv[n * HC + lane] = acc;
        else           gl[n * HC + (lane - HC)] = acc;
    }
}

// K2a: r1 = relu(sconv(cv, Wr1) + br1)
__global__ __launch_bounds__(512, 4) void k2a_conv(
    const float* __restrict__ cv, const int* __restrict__ nbr,
    const float* __restrict__ Wr1, const float* __restrict__ br1,
    float* __restrict__ r1, long long N)
{
    __shared__ u32 wlds[26*512];
    stage_w26(Wr1, wlds, 512);
    __syncthreads();
    const int lane = threadIdx.x & 63, o = lane & 31, h = lane >> 5;
    float ws[16]; load_self(Wr1, ws, o, h);
    const float bias = br1[o];
    const long long wave = (long long)blockIdx.x*8 + (threadIdx.x>>6);
    long long n0 = wave*CPT, n1 = n0+CPT; if (n1 > N) n1 = N;
    if (n0 >= n1) return;
    int pidx = (lane < 27 && lane != 13) ? nbr[(long long)lane*N + n0] : -1;
    float pself = cv[n0*HC + o];
    for (long long n = n0; n < n1; ++n) {
        int idxv = pidx; float selfv = pself;
        u64 mask = __ballot(idxv >= 0);
        if (n+1 < n1) {
            pidx = (lane < 27 && lane != 13) ? nbr[(long long)lane*N + n+1] : -1;
            pself = cv[(n+1)*HC + o];
        }
        float acc = conv_pt(cv, selfv, idxv, mask, wlds, ws, o, h);
        float v = fmaxf(acc + bias, 0.f);
        if (lane < HC) r1[n*HC + o] = v;
    }
}

// K2b: fused q-convs: out1/out2 from gl with (Wq1,Wq2) packed per u32
__global__ __launch_bounds__(1024, 4) void k2b_conv(
    const float* __restrict__ gl, const int* __restrict__ nbr,
    const float* __restrict__ Wq1, const float* __restrict__ bq1,
    const float* __restrict__ Wq2, const float* __restrict__ bq2,
    const int* __restrict__ batch_id,
    float* __restrict__ s12, float* __restrict__ m1, float* __restrict__ bsum,
    long long N)
{
    __shared__ u32 wlds[26*1024];
    __shared__ float lbs[256];
    for (int i = threadIdx.x; i < 26*1024; i += 1024) {
        int o = i & 31, c = (i >> 5) & 31, kp = i >> 10;
        int k = kp + (kp >= 13 ? 1 : 0);
        wlds[i] = (u32)f2bf(Wq1[k*1024 + c*32 + o]) | ((u32)f2bf(Wq2[k*1024 + c*32 + o]) << 16);
    }
    if (threadIdx.x < 256) lbs[threadIdx.x] = 0.f;
    __syncthreads();
    const int lane = threadIdx.x & 63, o = lane & 31, h = lane >> 5;
    float w1s[16], w2s[16];
    #pragma unroll
    for (int cc = 0; cc < 16; ++cc) {
        w1s[cc] = Wq1[13*1024 + (h*16+cc)*32 + o];
        w2s[cc] = Wq2[13*1024 + (h*16+cc)*32 + o];
    }
    const float b1 = bq1[o], b2 = bq2[o];
    const long long wave = (long long)blockIdx.x*16 + (threadIdx.x>>6);
    long long n0 = wave*CPT, n1 = n0+CPT; if (n1 > N) n1 = N;
    int pidx = -1; float pself = 0.f;
    if (n0 < n1) {
        pidx = (lane < 27 && lane != 13) ? nbr[(long long)lane*N + n0] : -1;
        pself = gl[n0*HC + o];
    }
    for (long long n = n0; n < n1; ++n) {
        int idxv = pidx; float selfv = pself;
        u64 mask = __ballot(idxv >= 0);
        if (n+1 < n1) {
            pidx = (lane < 27 && lane != 13) ? nbr[(long long)lane*N + n+1] : -1;
            pself = gl[(n+1)*HC + o];
        }
        float acc1 = 0.f, acc2 = 0.f;
        int k = -1; float rowv = 0.f;
        if (mask) {
            k = (int)__builtin_ctzll(mask); mask &= mask-1;
            int idx = __shfl(idxv, k, 64);
            rowv = gl[(long long)idx*HC + o];
        }
        #pragma unroll
        for (int cc = 0; cc < 16; ++cc) {
            float xv = __shfl(selfv, h*16+cc, 64);
            acc1 = fmaf(w1s[cc], xv, acc1);
            acc2 = fmaf(w2s[cc], xv, acc2);
        }
        while (k >= 0) {
            int kn = -1; float rown = 0.f;
            if (mask) {
                kn = (int)__builtin_ctzll(mask); mask &= mask-1;
                int idx = __shfl(idxv, kn, 64);
                rown = gl[(long long)idx*HC + o];
            }
            int ks = k - (k > 13 ? 1 : 0);
            const u32* wp = wlds + ks*1024 + h*512 + o;
            #pragma unroll
            for (int cc = 0; cc < 16; ++cc) {
                u32 wv = wp[cc*32];
                float xv = __shfl(rowv, h*16+cc, 64);
                acc1 = fmaf(u2f(wv << 16), xv, acc1);
                acc2 = fmaf(u2f(wv & 0xffff0000u), xv, acc2);
            }
            k = kn; rowv = rown;
        }
        acc1 += __shfl_xor(acc1, 32, 64);
        acc2 += __shfl_xor(acc2, 32, 64);
        float o1 = fmaxf(acc1 + b1, 0.f);
        float o2 = fmaxf(acc2 + b2, 0.f);
        float sm = o1;
        #pragma unroll
        for (int d = 1; d < 32; d <<= 1) sm += __shfl_xor(sm, d, 64);
        int b = batch_id[n];
        if (lane < HC) {
            s12[n*HC + o] = o1 + o2;
            atomicAdd(&lbs[b*HC + o], o2);
        }
        if (lane == 0) m1[n] = sm * (1.f/32.f);
    }
    __syncthreads();
    if (threadIdx.x < 256) atomicAdd(&bsum[threadIdx.x], lbs[threadIdx.x]);
}

// K3a: r2 = relu(sconv(r1, Wr2) + br2); cv <- r2 + 2*cv  (in place)
__global__ __launch_bounds__(512, 4) void k3a_conv(
    const float* __restrict__ r1, const int* __restrict__ nbr,
    const float* __restrict__ Wr2, const float* __restrict__ br2,
    float* __restrict__ cv, long long N)
{
    __shared__ u32 wlds[26*512];
    stage_w26(Wr2, wlds, 512);
    __syncthreads();
    const int lane = threadIdx.x & 63, o = lane & 31, h = lane >> 5;
    float ws[16]; load_self(Wr2, ws, o, h);
    const float bias = br2[o];
    const long long wave = (long long)blockIdx.x*8 + (threadIdx.x>>6);
    long long n0 = wave*CPT, n1 = n0+CPT; if (n1 > N) n1 = N;
    if (n0 >= n1) return;
    int pidx = (lane < 27 && lane != 13) ? nbr[(long long)lane*N + n0] : -1;
    float pself = r1[n0*HC + o];
    float pcv = cv[n0*HC + o];
    for (long long n = n0; n < n1; ++n) {
        int idxv = pidx; float selfv = pself; float cvv = pcv;
        u64 mask = __ballot(idxv >= 0);
        if (n+1 < n1) {
            pidx = (lane < 27 && lane != 13) ? nbr[(long long)lane*N + n+1] : -1;
            pself = r1[(n+1)*HC + o];
            pcv = cv[(n+1)*HC + o];
        }
        float acc = conv_pt(r1, selfv, idxv, mask, wlds, ws, o, h);
        float r2 = fmaxf(acc + bias, 0.f);
        if (lane < HC) cv[n*HC + o] = r2 + 2.f*cvv;
    }
}

// K3b: epilogue
__global__ __launch_bounds__(256, 3) void k3b_epi(
    const float* __restrict__ cx2, const float* __restrict__ gl,
    const float* __restrict__ s12, const float* __restrict__ m1,
    const float* __restrict__ bsum, const int* __restrict__ batch_id,
    const float* __restrict__ Wq3, const float* __restrict__ bq3,
    const float* __restrict__ Wg2, const float* __restrict__ bg2,
    const float* __restrict__ x, float* __restrict__ out,
    long long N, const int* __restrict__ bsz)
{
    const int lane = threadIdx.x & 63, o = lane & 31;
    const long long wave = (long long)blockIdx.x * 4 + (threadIdx.x >> 6);
    const int C3 = 32;
    long long n0 = wave * C3;
    if (n0 >= N) return;
    long long n1 = n0 + C3; if (n1 > N) n1 = N;
    float wq3c[32], wg2c[64];
    #pragma unroll
    for (int c = 0; c < 32; ++c) wq3c[c] = Wq3[c * 32 + o];
    #pragma unroll
    for (int c = 0; c < 64; ++c) wg2c[c] = Wg2[c * 64 + lane];
    const float bq3v = bq3[o];
    const float bg2v = bg2[lane];
    const float invNP = (float)(*bsz) / (float)N;
    for (long long n = n0; n < n1; ++n) {
        float cxv = cx2[n*HC + o];
        float glv = gl[n*HC + o];
        int b = batch_id[n];
        float m2v = bsum[b*HC + o] * invNP;
        float fin = sqrtf(m1[n] * m2v + 1e-12f) + s12[n*HC + o];
        float facc = bq3v;
        #pragma unroll
        for (int c = 0; c < 32; ++c) facc = fmaf(__shfl(fin, c, 64), wq3c[c], facc);
        float f = fmaxf(facc, 0.f);
        float glo = fmaxf(glv - f, 0.f);
        float racc = bg2v;
        #pragma unroll
        for (int c = 0; c < 32; ++c) racc = fmaf(__shfl(cxv, c, 64), wg2c[c], racc);
        #pragma unroll
        for (int c = 0; c < 32; ++c) racc = fmaf(__shfl(glo, c, 64), wg2c[32 + c], racc);
        out[n * 64 + lane] = x[n * 64 + lane] + racc;
    }
}

extern "C" void kernel_launch(void* const* d_in, const int* in_sizes, int n_in,
                              void* d_out, int out_size, void* d_ws, size_t ws_size,
                              hipStream_t stream) {
    const float* x   = (const float*)d_in[0];
    const float* Wg1 = (const float*)d_in[1];
    const float* bg1 = (const float*)d_in[2];
    const float* Wg2 = (const float*)d_in[3];
    const float* bg2 = (const float*)d_in[4];
    const float* Wr1 = (const float*)d_in[5];
    const float* br1 = (const float*)d_in[6];
    const float* Wr2 = (const float*)d_in[7];
    const float* br2 = (const float*)d_in[8];
    const float* Wq1 = (const float*)d_in[9];
    const float* bq1 = (const float*)d_in[10];
    const float* Wq2 = (const float*)d_in[11];
    const float* bq2 = (const float*)d_in[12];
    const float* Wq3 = (const float*)d_in[13];
    const float* bq3 = (const float*)d_in[14];
    const int* nbr   = (const int*)d_in[15];
    const int* bid   = (const int*)d_in[16];
    const int* bsz   = (const int*)d_in[17];

    const long long N = (long long)in_sizes[0] / 64;

    float* cv   = (float*)d_ws;          // becomes cx2 after k3a
    float* gl   = cv  + N * 32;
    float* r1   = gl  + N * 32;
    float* s12  = r1  + N * 32;
    float* m1   = s12 + N * 32;
    float* bsum = m1  + N;               // 256 floats

    float* out = (float*)d_out;

    hipMemsetAsync(bsum, 0, 256 * sizeof(float), stream);

    {
        long long waves = (N + 31) / 32;
        int blocks = (int)((waves + 3) / 4);
        k1_gemm<<<blocks, 256, 0, stream>>>(x, Wg1, bg1, cv, gl, N);
    }
    long long cwaves = (N + CPT - 1) / CPT;
    int blk8  = (int)((cwaves + 7) / 8);
    int blk16 = (int)((cwaves + 15) / 16);
    k2a_conv<<<blk8, 512, 0, stream>>>(cv, nbr, Wr1, br1, r1, N);
    k2b_conv<<<blk16, 1024, 0, stream>>>(gl, nbr, Wq1, bq1, Wq2, bq2, bid, s12, m1, bsum, N);
    k3a_conv<<<blk8, 512, 0, stream>>>(r1, nbr, Wr2, br2, cv, N);
    {
        long long waves = (N + 31) / 32;
        int blocks = (int)((waves + 3) / 4);
        k3b_epi<<<blocks, 256, 0, stream>>>(cv, gl, s12, m1, bsum, bid,
                                            Wq3, bq3, Wg2, bg2, x, out, N, bsz);
    }
}

// Round 5
// 399.738 us; speedup vs baseline: 5.3141x; 1.9779x over previous
//
#include <hip/hip_runtime.h>
#include <stdint.h>

typedef unsigned int u32;
typedef unsigned short u16;
typedef unsigned long long u64;
typedef __attribute__((ext_vector_type(8))) short bf16x8;
typedef __attribute__((ext_vector_type(4))) float f32x4;

#define HC 32
#define CPT 16   // points per wave in conv kernels

__device__ __forceinline__ float u2f(u32 u){ union{u32 i;float f;}v; v.i=u; return v.f; }
__device__ __forceinline__ u16 f2bf(float f){ union{float f;u32 i;}v; v.f=f; u32 i=v.i;
    return (u16)((i + 0x7FFFu + ((i>>16)&1u))>>16); }  // RNE
__device__ __forceinline__ short bfs(float f){ return (short)f2bf(f); }

// ---- sparse-conv machinery (unchanged from round 4) ----
__device__ __forceinline__ void stage_w26(const float* __restrict__ W, u32* __restrict__ wl, int nthr) {
    for (int i = threadIdx.x; i < 26*512; i += nthr) {
        int o = i & 31, row = (i >> 5) & 15, kp = i >> 9;
        int k = kp + (kp >= 13 ? 1 : 0);
        int c0 = (row >> 3)*16 + (row & 7)*2;
        float a = W[k*1024 + c0*32 + o];
        float b = W[k*1024 + (c0+1)*32 + o];
        wl[i] = (u32)f2bf(a) | ((u32)f2bf(b) << 16);
    }
}

__device__ __forceinline__ void load_self(const float* __restrict__ W, float* ws, int o, int h) {
    #pragma unroll
    for (int cc = 0; cc < 16; ++cc) ws[cc] = W[13*1024 + (h*16+cc)*32 + o];
}

__device__ __forceinline__ float conv_pt(
    const float* __restrict__ src, float selfv, int idxv, u64 mask,
    const u32* __restrict__ wl, const float* __restrict__ ws, int o, int h)
{
    float acc = 0.f;
    int k = -1; float rowv = 0.f;
    if (mask) {
        k = (int)__builtin_ctzll(mask); mask &= mask-1;
        int idx = __shfl(idxv, k, 64);
        rowv = src[(long long)idx*HC + o];
    }
    #pragma unroll
    for (int cc = 0; cc < 16; ++cc)
        acc = fmaf(ws[cc], __shfl(selfv, h*16+cc, 64), acc);
    while (k >= 0) {
        int kn = -1; float rown = 0.f;
        if (mask) {
            kn = (int)__builtin_ctzll(mask); mask &= mask-1;
            int idx = __shfl(idxv, kn, 64);
            rown = src[(long long)idx*HC + o];
        }
        int ks = k - (k > 13 ? 1 : 0);
        const u32* wp = wl + ks*512 + h*256 + o;
        #pragma unroll
        for (int cc2 = 0; cc2 < 8; ++cc2) {
            u32 wv = wp[cc2*32];
            float xv0 = __shfl(rowv, h*16 + 2*cc2, 64);
            float xv1 = __shfl(rowv, h*16 + 2*cc2 + 1, 64);
            acc = fmaf(u2f(wv << 16), xv0, acc);
            acc = fmaf(u2f(wv & 0xffff0000u), xv1, acc);
        }
        k = kn; rowv = rown;
    }
    acc += __shfl_xor(acc, 32, 64);
    return acc;
}

// ---- K1: y = x @ Wg1 + bg1 -> cv | gl  (MFMA, 16-pt tiles, 4 tiles/wave) ----
__global__ __launch_bounds__(256) void k1_mfma(
    const float* __restrict__ x, const float* __restrict__ Wg1, const float* __restrict__ bg1,
    float* __restrict__ cv, float* __restrict__ gl, long long N)
{
    const int lane = threadIdx.x & 63;
    const int m = lane & 15, g = lane >> 4;
    bf16x8 bw[4][2];
    #pragma unroll
    for (int no = 0; no < 4; ++no)
      #pragma unroll
      for (int kf = 0; kf < 2; ++kf)
        #pragma unroll
        for (int j = 0; j < 8; ++j)
            bw[no][kf][j] = bfs(Wg1[(kf*32 + g*8 + j)*64 + no*16 + m]);
    float bias4[4];
    #pragma unroll
    for (int no = 0; no < 4; ++no) bias4[no] = bg1[no*16 + m];

    const long long wave = (long long)blockIdx.x*4 + (threadIdx.x>>6);
    long long t0 = wave * 4;
    #pragma unroll 1
    for (long long t = t0; t < t0+4; ++t) {
        long long p0 = t*16;
        if (p0 >= N) break;
        long long pr_a = p0 + m; if (pr_a > N-1) pr_a = N-1;
        const float4* xr = (const float4*)(x + pr_a*64);
        bf16x8 aw[2];
        #pragma unroll
        for (int kf = 0; kf < 2; ++kf) {
            float4 lo = xr[kf*8 + g*2];
            float4 hi = xr[kf*8 + g*2 + 1];
            aw[kf][0]=bfs(lo.x); aw[kf][1]=bfs(lo.y); aw[kf][2]=bfs(lo.z); aw[kf][3]=bfs(lo.w);
            aw[kf][4]=bfs(hi.x); aw[kf][5]=bfs(hi.y); aw[kf][6]=bfs(hi.z); aw[kf][7]=bfs(hi.w);
        }
        #pragma unroll
        for (int no = 0; no < 4; ++no) {
            f32x4 acc = {0.f,0.f,0.f,0.f};
            acc = __builtin_amdgcn_mfma_f32_16x16x32_bf16(aw[0], bw[no][0], acc, 0,0,0);
            acc = __builtin_amdgcn_mfma_f32_16x16x32_bf16(aw[1], bw[no][1], acc, 0,0,0);
            #pragma unroll
            for (int j = 0; j < 4; ++j) {
                long long pr = p0 + g*4 + j;
                if (pr < N) {
                    float v = acc[j] + bias4[no];
                    if (no < 2) cv[pr*32 + no*16 + m] = v;
                    else        gl[pr*32 + (no-2)*16 + m] = v;
                }
            }
        }
    }
}

// K2a: r1 = relu(sconv(cv, Wr1) + br1)
__global__ __launch_bounds__(512, 4) void k2a_conv(
    const float* __restrict__ cv, const int* __restrict__ nbr,
    const float* __restrict__ Wr1, const float* __restrict__ br1,
    float* __restrict__ r1, long long N)
{
    __shared__ u32 wlds[26*512];
    stage_w26(Wr1, wlds, 512);
    __syncthreads();
    const int lane = threadIdx.x & 63, o = lane & 31, h = lane >> 5;
    float ws[16]; load_self(Wr1, ws, o, h);
    const float bias = br1[o];
    const long long wave = (long long)blockIdx.x*8 + (threadIdx.x>>6);
    long long n0 = wave*CPT, n1 = n0+CPT; if (n1 > N) n1 = N;
    if (n0 >= n1) return;
    int pidx = (lane < 27 && lane != 13) ? nbr[(long long)lane*N + n0] : -1;
    float pself = cv[n0*HC + o];
    for (long long n = n0; n < n1; ++n) {
        int idxv = pidx; float selfv = pself;
        u64 mask = __ballot(idxv >= 0);
        if (n+1 < n1) {
            pidx = (lane < 27 && lane != 13) ? nbr[(long long)lane*N + n+1] : -1;
            pself = cv[(n+1)*HC + o];
        }
        float acc = conv_pt(cv, selfv, idxv, mask, wlds, ws, o, h);
        float v = fmaxf(acc + bias, 0.f);
        if (lane < HC) r1[n*HC + o] = v;
    }
}

// K2b: fused q-convs
__global__ __launch_bounds__(1024, 4) void k2b_conv(
    const float* __restrict__ gl, const int* __restrict__ nbr,
    const float* __restrict__ Wq1, const float* __restrict__ bq1,
    const float* __restrict__ Wq2, const float* __restrict__ bq2,
    const int* __restrict__ batch_id,
    float* __restrict__ s12, float* __restrict__ m1, float* __restrict__ bsum,
    long long N)
{
    __shared__ u32 wlds[26*1024];
    __shared__ float lbs[256];
    for (int i = threadIdx.x; i < 26*1024; i += 1024) {
        int o = i & 31, c = (i >> 5) & 31, kp = i >> 10;
        int k = kp + (kp >= 13 ? 1 : 0);
        wlds[i] = (u32)f2bf(Wq1[k*1024 + c*32 + o]) | ((u32)f2bf(Wq2[k*1024 + c*32 + o]) << 16);
    }
    if (threadIdx.x < 256) lbs[threadIdx.x] = 0.f;
    __syncthreads();
    const int lane = threadIdx.x & 63, o = lane & 31, h = lane >> 5;
    float w1s[16], w2s[16];
    #pragma unroll
    for (int cc = 0; cc < 16; ++cc) {
        w1s[cc] = Wq1[13*1024 + (h*16+cc)*32 + o];
        w2s[cc] = Wq2[13*1024 + (h*16+cc)*32 + o];
    }
    const float b1 = bq1[o], b2 = bq2[o];
    const long long wave = (long long)blockIdx.x*16 + (threadIdx.x>>6);
    long long n0 = wave*CPT, n1 = n0+CPT; if (n1 > N) n1 = N;
    int pidx = -1; float pself = 0.f;
    if (n0 < n1) {
        pidx = (lane < 27 && lane != 13) ? nbr[(long long)lane*N + n0] : -1;
        pself = gl[n0*HC + o];
    }
    for (long long n = n0; n < n1; ++n) {
        int idxv = pidx; float selfv = pself;
        u64 mask = __ballot(idxv >= 0);
        if (n+1 < n1) {
            pidx = (lane < 27 && lane != 13) ? nbr[(long long)lane*N + n+1] : -1;
            pself = gl[(n+1)*HC + o];
        }
        float acc1 = 0.f, acc2 = 0.f;
        int k = -1; float rowv = 0.f;
        if (mask) {
            k = (int)__builtin_ctzll(mask); mask &= mask-1;
            int idx = __shfl(idxv, k, 64);
            rowv = gl[(long long)idx*HC + o];
        }
        #pragma unroll
        for (int cc = 0; cc < 16; ++cc) {
            float xv = __shfl(selfv, h*16+cc, 64);
            acc1 = fmaf(w1s[cc], xv, acc1);
            acc2 = fmaf(w2s[cc], xv, acc2);
        }
        while (k >= 0) {
            int kn = -1; float rown = 0.f;
            if (mask) {
                kn = (int)__builtin_ctzll(mask); mask &= mask-1;
                int idx = __shfl(idxv, kn, 64);
                rown = gl[(long long)idx*HC + o];
            }
            int ks = k - (k > 13 ? 1 : 0);
            const u32* wp = wlds + ks*1024 + h*512 + o;
            #pragma unroll
            for (int cc = 0; cc < 16; ++cc) {
                u32 wv = wp[cc*32];
                float xv = __shfl(rowv, h*16+cc, 64);
                acc1 = fmaf(u2f(wv << 16), xv, acc1);
                acc2 = fmaf(u2f(wv & 0xffff0000u), xv, acc2);
            }
            k = kn; rowv = rown;
        }
        acc1 += __shfl_xor(acc1, 32, 64);
        acc2 += __shfl_xor(acc2, 32, 64);
        float o1 = fmaxf(acc1 + b1, 0.f);
        float o2 = fmaxf(acc2 + b2, 0.f);
        float sm = o1;
        #pragma unroll
        for (int d = 1; d < 32; d <<= 1) sm += __shfl_xor(sm, d, 64);
        int b = batch_id[n];
        if (lane < HC) {
            s12[n*HC + o] = o1 + o2;
            atomicAdd(&lbs[b*HC + o], o2);
        }
        if (lane == 0) m1[n] = sm * (1.f/32.f);
    }
    __syncthreads();
    if (threadIdx.x < 256) atomicAdd(&bsum[threadIdx.x], lbs[threadIdx.x]);
}

// K3a: r2 = relu(sconv(r1, Wr2) + br2); cv <- r2 + 2*cv
__global__ __launch_bounds__(512, 4) void k3a_conv(
    const float* __restrict__ r1, const int* __restrict__ nbr,
    const float* __restrict__ Wr2, const float* __restrict__ br2,
    float* __restrict__ cv, long long N)
{
    __shared__ u32 wlds[26*512];
    stage_w26(Wr2, wlds, 512);
    __syncthreads();
    const int lane = threadIdx.x & 63, o = lane & 31, h = lane >> 5;
    float ws[16]; load_self(Wr2, ws, o, h);
    const float bias = br2[o];
    const long long wave = (long long)blockIdx.x*8 + (threadIdx.x>>6);
    long long n0 = wave*CPT, n1 = n0+CPT; if (n1 > N) n1 = N;
    if (n0 >= n1) return;
    int pidx = (lane < 27 && lane != 13) ? nbr[(long long)lane*N + n0] : -1;
    float pself = r1[n0*HC + o];
    float pcv = cv[n0*HC + o];
    for (long long n = n0; n < n1; ++n) {
        int idxv = pidx; float selfv = pself; float cvv = pcv;
        u64 mask = __ballot(idxv >= 0);
        if (n+1 < n1) {
            pidx = (lane < 27 && lane != 13) ? nbr[(long long)lane*N + n+1] : -1;
            pself = r1[(n+1)*HC + o];
            pcv = cv[(n+1)*HC + o];
        }
        float acc = conv_pt(r1, selfv, idxv, mask, wlds, ws, o, h);
        float r2 = fmaxf(acc + bias, 0.f);
        if (lane < HC) cv[n*HC + o] = r2 + 2.f*cvv;
    }
}

// ---- K3b: epilogue via MFMA ----
__global__ __launch_bounds__(256) void k3b_mfma(
    const float* __restrict__ cx2, const float* __restrict__ gl,
    const float* __restrict__ s12, const float* __restrict__ m1,
    const float* __restrict__ bsum, const int* __restrict__ batch_id,
    const float* __restrict__ Wq3, const float* __restrict__ bq3,
    const float* __restrict__ Wg2, const float* __restrict__ bg2,
    const float* __restrict__ x, float* __restrict__ out,
    long long N, const int* __restrict__ bsz)
{
    __shared__ __align__(16) u16 finL[4][16*40];   // padded stride 40 u16
    __shared__ __align__(16) u16 a2L[4][16*72];    // padded stride 72 u16
    const int wid = threadIdx.x >> 6;
    u16* fin_bf = finL[wid];
    u16* a2_bf  = a2L[wid];
    const int lane = threadIdx.x & 63;
    const int m = lane & 15, g = lane >> 4;

    bf16x8 bq[2];
    #pragma unroll
    for (int no = 0; no < 2; ++no)
      #pragma unroll
      for (int j = 0; j < 8; ++j)
        bq[no][j] = bfs(Wq3[(g*8+j)*32 + no*16 + m]);
    bf16x8 bgw[4][2];
    #pragma unroll
    for (int no = 0; no < 4; ++no)
      #pragma unroll
      for (int kf = 0; kf < 2; ++kf)
        #pragma unroll
        for (int j = 0; j < 8; ++j)
          bgw[no][kf][j] = bfs(Wg2[(kf*32 + g*8 + j)*64 + no*16 + m]);
    const float bq3a = bq3[m], bq3b = bq3[16+m];
    float bgb[4];
    #pragma unroll
    for (int no = 0; no < 4; ++no) bgb[no] = bg2[no*16 + m];
    const float invNP = (float)(*bsz) / (float)N;
    const int p_lin = lane >> 2, c0 = (lane & 3) * 8;

    const long long wave = (long long)blockIdx.x*4 + wid;
    long long t0 = wave*4;
    #pragma unroll 1
    for (long long t = t0; t < t0+4; ++t) {
        long long p0 = t*16;
        if (p0 >= N) break;
        long long pp = p0 + p_lin; if (pp > N-1) pp = N-1;
        // phase A: compute fin, stage fin + cx2 (bf16) to LDS
        float m1v = m1[pp];
        int b = batch_id[pp];
        const float4* bsp = (const float4*)(bsum + b*32 + c0);
        float4 bs0 = bsp[0], bs1 = bsp[1];
        const float4* s12p = (const float4*)(s12 + pp*32 + c0);
        float4 s0 = s12p[0], s1 = s12p[1];
        const float4* cxp = (const float4*)(cx2 + pp*32 + c0);
        float4 cva = cxp[0], cvb = cxp[1];
        float bsv[8] = {bs0.x,bs0.y,bs0.z,bs0.w,bs1.x,bs1.y,bs1.z,bs1.w};
        float sv[8]  = {s0.x,s0.y,s0.z,s0.w,s1.x,s1.y,s1.z,s1.w};
        float cxv[8] = {cva.x,cva.y,cva.z,cva.w,cvb.x,cvb.y,cvb.z,cvb.w};
        bf16x8 fbv, cbv;
        #pragma unroll
        for (int j = 0; j < 8; ++j) {
            float enc = sqrtf(m1v * bsv[j] * invNP + 1e-12f);
            fbv[j] = bfs(enc + sv[j]);
            cbv[j] = bfs(cxv[j]);
        }
        *(bf16x8*)&fin_bf[p_lin*40 + c0] = fbv;
        *(bf16x8*)&a2_bf[p_lin*72 + c0] = cbv;
        asm volatile("s_waitcnt lgkmcnt(0)" ::: "memory");
        // phase B: f = fin @ Wq3
        bf16x8 af = *(const bf16x8*)&fin_bf[m*40 + g*8];
        f32x4 f0 = {0.f,0.f,0.f,0.f}, f1 = {0.f,0.f,0.f,0.f};
        f0 = __builtin_amdgcn_mfma_f32_16x16x32_bf16(af, bq[0], f0, 0,0,0);
        f1 = __builtin_amdgcn_mfma_f32_16x16x32_bf16(af, bq[1], f1, 0,0,0);
        // phase C: glo = relu(gl - relu(f+bq3)) -> a2 cols 32..63
        #pragma unroll
        for (int j = 0; j < 4; ++j) {
            int row = g*4 + j;
            long long pr = p0 + row; if (pr > N-1) pr = N-1;
            float fa = fmaxf(f0[j] + bq3a, 0.f);
            float fb = fmaxf(f1[j] + bq3b, 0.f);
            float g0 = fmaxf(gl[pr*32 + m] - fa, 0.f);
            float g1 = fmaxf(gl[pr*32 + 16 + m] - fb, 0.f);
            a2_bf[row*72 + 32 + m] = f2bf(g0);
            a2_bf[row*72 + 48 + m] = f2bf(g1);
        }
        asm volatile("s_waitcnt lgkmcnt(0)" ::: "memory");
        // phase D: out = x + [cx2|glo] @ Wg2 + bg2
        bf16x8 a20 = *(const bf16x8*)&a2_bf[m*72 + g*8];
        bf16x8 a21 = *(const bf16x8*)&a2_bf[m*72 + 32 + g*8];
        #pragma unroll
        for (int no = 0; no < 4; ++no) {
            f32x4 acc = {0.f,0.f,0.f,0.f};
            acc = __builtin_amdgcn_mfma_f32_16x16x32_bf16(a20, bgw[no][0], acc, 0,0,0);
            acc = __builtin_amdgcn_mfma_f32_16x16x32_bf16(a21, bgw[no][1], acc, 0,0,0);
            #pragma unroll
            for (int j = 0; j < 4; ++j) {
                long long pr = p0 + g*4 + j;
                if (pr < N)
                    out[pr*64 + no*16 + m] = x[pr*64 + no*16 + m] + acc[j] + bgb[no];
            }
        }
    }
}

extern "C" void kernel_launch(void* const* d_in, const int* in_sizes, int n_in,
                              void* d_out, int out_size, void* d_ws, size_t ws_size,
                              hipStream_t stream) {
    const float* x   = (const float*)d_in[0];
    const float* Wg1 = (const float*)d_in[1];
    const float* bg1 = (const float*)d_in[2];
    const float* Wg2 = (const float*)d_in[3];
    const float* bg2 = (const float*)d_in[4];
    const float* Wr1 = (const float*)d_in[5];
    const float* br1 = (const float*)d_in[6];
    const float* Wr2 = (const float*)d_in[7];
    const float* br2 = (const float*)d_in[8];
    const float* Wq1 = (const float*)d_in[9];
    const float* bq1 = (const float*)d_in[10];
    const float* Wq2 = (const float*)d_in[11];
    const float* bq2 = (const float*)d_in[12];
    const float* Wq3 = (const float*)d_in[13];
    const float* bq3 = (const float*)d_in[14];
    const int* nbr   = (const int*)d_in[15];
    const int* bid   = (const int*)d_in[16];
    const int* bsz   = (const int*)d_in[17];

    const long long N = (long long)in_sizes[0] / 64;

    float* cv   = (float*)d_ws;          // becomes cx2 after k3a
    float* gl   = cv  + N * 32;
    float* r1   = gl  + N * 32;
    float* s12  = r1  + N * 32;
    float* m1   = s12 + N * 32;
    float* bsum = m1  + N;               // 256 floats

    float* out = (float*)d_out;

    hipMemsetAsync(bsum, 0, 256 * sizeof(float), stream);

    long long tiles = (N + 15) / 16;
    long long gwaves = (tiles + 3) / 4;        // 4 tiles per wave
    int gblocks = (int)((gwaves + 3) / 4);     // 4 waves per block

    k1_mfma<<<gblocks, 256, 0, stream>>>(x, Wg1, bg1, cv, gl, N);

    long long cwaves = (N + CPT - 1) / CPT;
    int blk8  = (int)((cwaves + 7) / 8);
    int blk16 = (int)((cwaves + 15) / 16);
    k2a_conv<<<blk8, 512, 0, stream>>>(cv, nbr, Wr1, br1, r1, N);
    k2b_conv<<<blk16, 1024, 0, stream>>>(gl, nbr, Wq1, bq1, Wq2, bq2, bid, s12, m1, bsum, N);
    k3a_conv<<<blk8, 512, 0, stream>>>(r1, nbr, Wr2, br2, cv, N);

    k3b_mfma<<<gblocks, 256, 0, stream>>>(cv, gl, s12, m1, bsum, bid,
                                          Wq3, bq3, Wg2, bg2, x, out, N, bsz);
}